// Round 17
// baseline (257.203 us; speedup 1.0000x reference)
//
#include <hip/hip_runtime.h>

typedef _Float16 f16;
typedef __attribute__((ext_vector_type(8))) _Float16 f16x8;
typedef __attribute__((ext_vector_type(4))) _Float16 f16x4;
typedef __attribute__((ext_vector_type(4))) float f32x4;
typedef __attribute__((ext_vector_type(16))) float f32x16;

#define BATCH 16
#define NSEQ  2048
#define DDIM  300
#define DPK   328   // padded row length (f16) for row-major Xf/Yf (zeros in [300,328))
#define DPV   304   // padded d-rows for transposed XT/YT (row 300 = ONES, see below)
#define NTP   2056  // padded q-cols for transposed copies (zeros in [2048,2056))
#define XF_ELEMS (BATCH*NSEQ*DPK)
#define XT_ELEMS (BATCH*DPV*NTP)

__device__ __forceinline__ void gl_lds16(const void* g, void* l) {
  __builtin_amdgcn_global_load_lds((const __attribute__((address_space(1))) unsigned int*)g,
                                   (__attribute__((address_space(3))) unsigned int*)l, 16, 0, 0);
}

// ---------------------------------------------------------------------------
// Preprocess: X,Y f32 -> f16 row-major (padded) + f16 transposed (padded).
// Transposed pad row d==300 is set to 1.0: PV then accumulates sum(P) at the
// d=300 output position for free (ones-row lsum trick); rows 301..303 stay 0.
// ---------------------------------------------------------------------------
__global__ __launch_bounds__(256) void prep_kernel(const float* __restrict__ X,
                                                   const float* __restrict__ Y,
                                                   f16* __restrict__ Xf, f16* __restrict__ Yf,
                                                   f16* __restrict__ XT, f16* __restrict__ YT) {
  __shared__ float tile[32][33];
  int bz   = blockIdx.z;            // 0..31 = tensor*16 + b
  int tsel = bz >> 4, b = bz & 15;
  const float* src = tsel ? Y : X;
  f16* dF = tsel ? Yf : Xf;
  f16* dT = tsel ? YT : XT;
  int d0 = blockIdx.y * 32;
  int q0 = blockIdx.x * 32;
  int tid = threadIdx.x;
  int c = tid & 31, rr = tid >> 5;

  #pragma unroll
  for (int i = 0; i < 4; ++i) {
    int qr = rr + i * 8;
    int q = q0 + qr, d = d0 + c;
    float v = 0.f;
    if (q < NSEQ && d < DDIM) v = src[(size_t)b * NSEQ * DDIM + (size_t)q * DDIM + d];
    tile[c][qr] = v;
    if (q < NSEQ && d < DPK) dF[(size_t)b * NSEQ * DPK + (size_t)q * DPK + d] = (f16)v;
  }
  __syncthreads();
  #pragma unroll
  for (int i = 0; i < 4; ++i) {
    int dr = rr + i * 8;
    int d = d0 + dr, q = q0 + c;
    if (d < DPV && q < NTP) {
      float v = (d == DDIM) ? 1.0f : tile[dr][c];   // ones-row at d==300
      dT[(size_t)b * DPV * NTP + (size_t)d * NTP + q] = (f16)v;
    }
  }
}

// ---------------------------------------------------------------------------
// Flash attention v17 = R16 (32x32x16 MFMA, 230 us) + ones-row lsum:
// V^T row 300 = 1.0 -> member1's O[4][12] (d=300 position, hi=1 lanes)
// accumulates sum_kv P[q][kv] with defer-max rescales applied automatically.
// Deletes the 16-deep serial l+=e add chain from the exposed exp section and
// the epilogue partial reduce; l now exactly consistent with O's f16 P.
// Everything else identical to R16: 8 waves = 4 qg x 2 members, QBLK=128,
// KVBLK=64, kv-split QK^T + d-split PV (member1 d 144..303), K dbuf / V
// single (staged after B1), phase1 PV/QK half-interleave, 2 barriers/iter.
// LDS 147200 B. Grid 512 XCD-swizzled. __launch_bounds__(512,1).
// ---------------------------------------------------------------------------
__global__ __launch_bounds__(512, 1) void attn_kernel(const f16* __restrict__ Xf,
                                                      const f16* __restrict__ Yf,
                                                      const f16* __restrict__ XT,
                                                      const f16* __restrict__ YT,
                                                      float* __restrict__ out) {
  __shared__ __align__(16) f16 Ksh[2][64][DPK];   // 83968 B (656 B rows)
  __shared__ __align__(16) f16 VTsh[DPV][72];     // 43776 B (144 B rows, single)
  __shared__ __align__(16) f16 Psh[4][32][72];    // 18432 B per-qg P (144 B rows)
  __shared__ float MxS[4][2][32];                 //  1024 B max/lsum exchange
                                                  // total 147200 B

  int idx = blockIdx.x;
  int swz = (idx & 7) * 64 + (idx >> 3);          // 512 % 8 == 0: bijective XCD chunking
  int qt  = swz & 15;
  int b   = (swz >> 4) & 15;
  int dir = swz >> 8;

  const f16* Qsrc = dir ? Yf : Xf;
  const f16* Ksrc = dir ? Xf : Yf;
  const f16* Vts  = dir ? XT : YT;   // V^T source [DPV][NTP]

  const size_t bq = (size_t)b * NSEQ * DPK;
  const size_t bt = (size_t)b * DPV * NTP;

  int tid = threadIdx.x;
  int lane = tid & 63, wid = tid >> 6;
  int qg = wid >> 1, mem = wid & 1;
  int l31 = lane & 31, hi = lane >> 5;
  int qbase = qt * 128 + qg * 32;     // q-group's 32 rows (shared by both members)

  // Q fragments (B-operand, 32x32x16): lane = Q[q=qbase+l31][ks*16 + hi*8 + j]
  f16x8 qf[20];
  {
    const f16* qrow = Qsrc + bq + (size_t)(qbase + l31) * DPK + hi * 8;
    #pragma unroll
    for (int ks = 0; ks < 20; ++ks) qf[ks] = *(const f16x8*)(qrow + ks * 16);
  }

  const int dbase = mem ? 144 : 0;    // PV d-tile base (member1 overlaps 144..159)
  const int dlo   = mem ? 160 : 0;    // first d this member STORES

  f32x16 O[5];
  #pragma unroll
  for (int dt = 0; dt < 5; ++dt)
    #pragma unroll
    for (int e = 0; e < 16; ++e) O[dt][e] = 0.f;
  float m = -3.0e38f;                 // per-lane (q = l31) running max

  const char* gK0 = (const char*)(Ksrc + bq);
  const char* gV0 = (const char*)(Vts + bt);

  auto stageK = [&](int tt, int buf) {           // 64 rows x 656 B = 2624 chunks
    const char* gK = gK0 + (size_t)tt * (64 * DPK * 2);
    char* lK = (char*)&Ksh[buf][0][0];
    #pragma unroll
    for (int i = 0; i < 6; ++i) {
      int c = i * 512 + tid;
      if (c < 2624) gl_lds16(gK + c * 16, lK + c * 16);
    }
  };
  auto stageV = [&](int tt) {                    // 304 rows x 9 slots (128 B data +
    const char* gV = gV0 + (size_t)tt * 128;     //  16 B benign overread) = 2736 chunks
    char* lV = (char*)&VTsh[0][0];
    #pragma unroll
    for (int i = 0; i < 6; ++i) {
      int c = i * 512 + tid;
      if (c < 2736) {
        int row = (int)((unsigned)c / 9u), slot = c - row * 9;
        gl_lds16(gV + (size_t)row * (NTP * 2) + slot * 16, lV + c * 16);
      }
    }
  };

  stageK(0, 0);                             // K[0] -> buf0
  asm volatile("s_waitcnt vmcnt(0)" ::: "memory");
  __builtin_amdgcn_s_barrier();
  __builtin_amdgcn_sched_barrier(0);

  #pragma unroll 1
  for (int t = 0; t < 32; ++t) {
    int kcur = t & 1;                       // K[t] buffer

    // ---- Phase 1: interleaved MFMA cluster — PV[t-1] / QK^T[t] half-blocks
    f32x16 S;
    #pragma unroll
    for (int e = 0; e < 16; ++e) S[e] = 0.f;
    __builtin_amdgcn_s_setprio(1);
    if (t > 0) {                            // PV half: ks 0,1 (kv 0..31 of tile t-1)
      #pragma unroll
      for (int ks = 0; ks < 2; ++ks) {
        f16x8 pf = *(const f16x8*)&Psh[qg][l31][ks * 16 + hi * 8];
        #pragma unroll
        for (int dt = 0; dt < 5; ++dt) {
          f16x8 vf = *(const f16x8*)&VTsh[dbase + dt * 32 + l31][ks * 16 + hi * 8];
          O[dt] = __builtin_amdgcn_mfma_f32_32x32x16_f16(vf, pf, O[dt], 0, 0, 0);
        }
      }
    }
    #pragma unroll
    for (int ks = 0; ks < 10; ++ks) {       // QK first half
      f16x8 a = *(const f16x8*)&Ksh[kcur][mem * 32 + l31][ks * 16 + hi * 8];
      S = __builtin_amdgcn_mfma_f32_32x32x16_f16(a, qf[ks], S, 0, 0, 0);
    }
    if (t > 0) {                            // PV half: ks 2,3 (kv 32..63)
      #pragma unroll
      for (int ks = 2; ks < 4; ++ks) {
        f16x8 pf = *(const f16x8*)&Psh[qg][l31][ks * 16 + hi * 8];
        #pragma unroll
        for (int dt = 0; dt < 5; ++dt) {
          f16x8 vf = *(const f16x8*)&VTsh[dbase + dt * 32 + l31][ks * 16 + hi * 8];
          O[dt] = __builtin_amdgcn_mfma_f32_32x32x16_f16(vf, pf, O[dt], 0, 0, 0);
        }
      }
    }
    #pragma unroll
    for (int ks = 10; ks < 20; ++ks) {      // QK second half
      f16x8 a = *(const f16x8*)&Ksh[kcur][mem * 32 + l31][ks * 16 + hi * 8];
      S = __builtin_amdgcn_mfma_f32_32x32x16_f16(a, qf[ks], S, 0, 0, 0);
    }
    __builtin_amdgcn_s_setprio(0);

    // ---- stage K[t+1] (dbuf; WAR-safe: buf readers finished before B2[t-1])
    if (t < 31) stageK(t + 1, kcur ^ 1);

    // ---- partial max over own 32 kv for q = l31 (16 in-lane + 1 shfl)
    float p = fmaxf(fmaxf(fmaxf(S[0], S[1]), S[2]),
                    fmaxf(fmaxf(S[3], S[4]), S[5]));
    p = fmaxf(p, fmaxf(fmaxf(S[6], S[7]), fmaxf(S[8], S[9])));
    p = fmaxf(p, fmaxf(fmaxf(S[10], S[11]), fmaxf(S[12], S[13])));
    p = fmaxf(p, fmaxf(S[14], S[15]));
    p = fmaxf(p, __shfl_xor(p, 32, 64));
    if (lane < 32) MxS[qg][mem][l31] = p;

    // ---- B1: Mx visible; all phase-1 reads of VTsh/Psh complete
    asm volatile("s_waitcnt lgkmcnt(0)" ::: "memory");
    __builtin_amdgcn_s_barrier();
    __builtin_amdgcn_sched_barrier(0);

    // ---- stage V[t] into the single buffer (race-free after B1)
    stageV(t);

    // ---- combine maxes, defer-max rescale, exp, P-write (no lsum adds:
    //      sum(P) accumulates in member1's O row 300 via the ones-row)
    float pp = MxS[qg][mem ^ 1][l31];
    float tm = fmaxf(p, pp);

    if (__any(tm > m + 8.0f)) {            // defer-max (identical in both members)
      float mn = fmaxf(m, tm), al = __expf(m - mn);
      #pragma unroll
      for (int dt = 0; dt < 5; ++dt)
        #pragma unroll
        for (int e = 0; e < 16; ++e) O[dt][e] *= al;
      m = mn;
    }

    #pragma unroll
    for (int r = 0; r < 4; ++r) {          // runs of 4 consecutive kv
      f16x4 h;
      #pragma unroll
      for (int j = 0; j < 4; ++j) {
        float e = __expf(S[4 * r + j] - m);   // bounded by e^8
        h[j] = (f16)e;
      }
      *(f16x4*)&Psh[qg][l31][mem * 32 + r * 8 + hi * 4] = h;
    }

    // ---- B2: P[t] visible; K[t+1] (issued ~2000 cyc ago) + V[t] drained
    asm volatile("s_waitcnt lgkmcnt(0) vmcnt(0)" ::: "memory");
    __builtin_amdgcn_s_barrier();
    __builtin_amdgcn_sched_barrier(0);
  }

  // ---- Epilogue PV[31] (trailing tile of the pipeline)
  {
    __builtin_amdgcn_s_setprio(1);
    #pragma unroll
    for (int ks = 0; ks < 4; ++ks) {
      f16x8 pf = *(const f16x8*)&Psh[qg][l31][ks * 16 + hi * 8];
      #pragma unroll
      for (int dt = 0; dt < 5; ++dt) {
        f16x8 vf = *(const f16x8*)&VTsh[dbase + dt * 32 + l31][ks * 16 + hi * 8];
        O[dt] = __builtin_amdgcn_mfma_f32_32x32x16_f16(vf, pf, O[dt], 0, 0, 0);
      }
    }
    __builtin_amdgcn_s_setprio(0);
  }

  // ---- lsum: member1's O[4][12] holds sum(P) at d=300 (hi=1 lanes only).
  //      Broadcast across hi, publish via MxS, both members read it.
  if (mem == 1) {
    float lt = O[4][12];
    float ls = __shfl_xor(lt, 32, 64);
    float l_tot = hi ? lt : ls;             // hi=0 lanes take partner's value
    if (lane < 32) MxS[qg][1][l31] = l_tot;
  }
  asm volatile("s_waitcnt lgkmcnt(0)" ::: "memory");
  __builtin_amdgcn_s_barrier();
  __builtin_amdgcn_sched_barrier(0);
  float rinv = 1.0f / MxS[qg][1][l31];

  // ---- store: d = dbase + dt*32 + r*8 + hi*4 + j (row 300 excluded by d0<300)
  {
    int q = qbase + l31;
    const f16* mrow = Qsrc + bq + (size_t)q * DPK;
    size_t orow = (size_t)b * (4096 * 300) + (size_t)(dir * 2048 + q) * 300;
    #pragma unroll
    for (int dt = 0; dt < 5; ++dt) {
      #pragma unroll
      for (int r = 0; r < 4; ++r) {
        int d0 = dbase + dt * 32 + r * 8 + hi * 4;
        if (d0 >= dlo && d0 < 300) {
          f16x4 mu = *(const f16x4*)(mrow + d0);
          f32x4 o;
          o[0] = O[dt][4 * r + 0] * rinv * (float)mu[0];
          o[1] = O[dt][4 * r + 1] * rinv * (float)mu[1];
          o[2] = O[dt][4 * r + 2] * rinv * (float)mu[2];
          o[3] = O[dt][4 * r + 3] * rinv * (float)mu[3];
          *(f32x4*)&out[orow + d0] = o;
        }
      }
    }
  }
}

extern "C" void kernel_launch(void* const* d_in, const int* in_sizes, int n_in,
                              void* d_out, int out_size, void* d_ws, size_t ws_size,
                              hipStream_t stream) {
  const float* X = (const float*)d_in[0];
  const float* Y = (const float*)d_in[1];
  float* out = (float*)d_out;

  size_t need = (size_t)(2 * XF_ELEMS + 2 * XT_ELEMS) * sizeof(f16);  // ~83 MB
  if (ws_size < need) return;

  // Layout: XT, YT first, Xf, Yf last — stageV's 16 B/row overread on the
  // transposed arrays lands in the following array, never past d_ws.
  f16* XT = (f16*)d_ws;
  f16* YT = XT + XT_ELEMS;
  f16* Xf = YT + XT_ELEMS;
  f16* Yf = Xf + XF_ELEMS;

  prep_kernel<<<dim3(65, 11, 32), 256, 0, stream>>>(X, Y, Xf, Yf, XT, YT);
  attn_kernel<<<dim3(512), 512, 0, stream>>>(Xf, Yf, XT, YT, out);
}

// Round 18
// 251.809 us; speedup vs baseline: 1.0214x; 1.0214x over previous
//
#include <hip/hip_runtime.h>

typedef _Float16 f16;
typedef __attribute__((ext_vector_type(8))) _Float16 f16x8;
typedef __attribute__((ext_vector_type(4))) _Float16 f16x4;
typedef __attribute__((ext_vector_type(4))) float f32x4;
typedef __attribute__((ext_vector_type(16))) float f32x16;

#define BATCH 16
#define NSEQ  2048
#define DDIM  300
#define DPK   328   // padded row length (f16) for row-major Xf/Yf (zeros in [300,328))
#define DPV   304   // padded d-rows for transposed XT/YT (row 300 = ONES, see below)
#define NTP   2056  // padded q-cols for transposed copies (zeros in [2048,2056))
#define XF_ELEMS (BATCH*NSEQ*DPK)
#define XT_ELEMS (BATCH*DPV*NTP)

__device__ __forceinline__ void gl_lds16(const void* g, void* l) {
  __builtin_amdgcn_global_load_lds((const __attribute__((address_space(1))) unsigned int*)g,
                                   (__attribute__((address_space(3))) unsigned int*)l, 16, 0, 0);
}

// ---------------------------------------------------------------------------
// Preprocess: X,Y f32 -> f16 row-major (padded) + f16 transposed (padded).
// Transposed pad row d==300 is set to 1.0: PV then accumulates sum(P) at the
// d=300 output position for free (ones-row lsum trick); rows 301..303 stay 0.
// ---------------------------------------------------------------------------
__global__ __launch_bounds__(256) void prep_kernel(const float* __restrict__ X,
                                                   const float* __restrict__ Y,
                                                   f16* __restrict__ Xf, f16* __restrict__ Yf,
                                                   f16* __restrict__ XT, f16* __restrict__ YT) {
  __shared__ float tile[32][33];
  int bz   = blockIdx.z;            // 0..31 = tensor*16 + b
  int tsel = bz >> 4, b = bz & 15;
  const float* src = tsel ? Y : X;
  f16* dF = tsel ? Yf : Xf;
  f16* dT = tsel ? YT : XT;
  int d0 = blockIdx.y * 32;
  int q0 = blockIdx.x * 32;
  int tid = threadIdx.x;
  int c = tid & 31, rr = tid >> 5;

  #pragma unroll
  for (int i = 0; i < 4; ++i) {
    int qr = rr + i * 8;
    int q = q0 + qr, d = d0 + c;
    float v = 0.f;
    if (q < NSEQ && d < DDIM) v = src[(size_t)b * NSEQ * DDIM + (size_t)q * DDIM + d];
    tile[c][qr] = v;
    if (q < NSEQ && d < DPK) dF[(size_t)b * NSEQ * DPK + (size_t)q * DPK + d] = (f16)v;
  }
  __syncthreads();
  #pragma unroll
  for (int i = 0; i < 4; ++i) {
    int dr = rr + i * 8;
    int d = d0 + dr, q = q0 + c;
    if (d < DPV && q < NTP) {
      float v = (d == DDIM) ? 1.0f : tile[dr][c];   // ones-row at d==300
      dT[(size_t)b * DPV * NTP + (size_t)d * NTP + q] = (f16)v;
    }
  }
}

// ---------------------------------------------------------------------------
// Flash attention v17 (repeat submission — cross-run noise measurement):
// 32x32x16 MFMA, ones-row lsum. 8 waves = 4 qg x 2 members, QBLK=128,
// KVBLK=64, kv-split QK^T + d-split PV (member1 d 144..303), K dbuf / V
// single (staged after B1), phase1 PV/QK half-interleave, 2 barriers/iter.
// attn dispatch is deterministic at ~228 us; total varies with prep's L3
// state (prep traffic floor: 184 MB => ~29 us cold / ~14 us warm).
// LDS 147200 B. Grid 512 XCD-swizzled. __launch_bounds__(512,1).
// ---------------------------------------------------------------------------
__global__ __launch_bounds__(512, 1) void attn_kernel(const f16* __restrict__ Xf,
                                                      const f16* __restrict__ Yf,
                                                      const f16* __restrict__ XT,
                                                      const f16* __restrict__ YT,
                                                      float* __restrict__ out) {
  __shared__ __align__(16) f16 Ksh[2][64][DPK];   // 83968 B (656 B rows)
  __shared__ __align__(16) f16 VTsh[DPV][72];     // 43776 B (144 B rows, single)
  __shared__ __align__(16) f16 Psh[4][32][72];    // 18432 B per-qg P (144 B rows)
  __shared__ float MxS[4][2][32];                 //  1024 B max/lsum exchange
                                                  // total 147200 B

  int idx = blockIdx.x;
  int swz = (idx & 7) * 64 + (idx >> 3);          // 512 % 8 == 0: bijective XCD chunking
  int qt  = swz & 15;
  int b   = (swz >> 4) & 15;
  int dir = swz >> 8;

  const f16* Qsrc = dir ? Yf : Xf;
  const f16* Ksrc = dir ? Xf : Yf;
  const f16* Vts  = dir ? XT : YT;   // V^T source [DPV][NTP]

  const size_t bq = (size_t)b * NSEQ * DPK;
  const size_t bt = (size_t)b * DPV * NTP;

  int tid = threadIdx.x;
  int lane = tid & 63, wid = tid >> 6;
  int qg = wid >> 1, mem = wid & 1;
  int l31 = lane & 31, hi = lane >> 5;
  int qbase = qt * 128 + qg * 32;     // q-group's 32 rows (shared by both members)

  // Q fragments (B-operand, 32x32x16): lane = Q[q=qbase+l31][ks*16 + hi*8 + j]
  f16x8 qf[20];
  {
    const f16* qrow = Qsrc + bq + (size_t)(qbase + l31) * DPK + hi * 8;
    #pragma unroll
    for (int ks = 0; ks < 20; ++ks) qf[ks] = *(const f16x8*)(qrow + ks * 16);
  }

  const int dbase = mem ? 144 : 0;    // PV d-tile base (member1 overlaps 144..159)
  const int dlo   = mem ? 160 : 0;    // first d this member STORES

  f32x16 O[5];
  #pragma unroll
  for (int dt = 0; dt < 5; ++dt)
    #pragma unroll
    for (int e = 0; e < 16; ++e) O[dt][e] = 0.f;
  float m = -3.0e38f;                 // per-lane (q = l31) running max

  const char* gK0 = (const char*)(Ksrc + bq);
  const char* gV0 = (const char*)(Vts + bt);

  auto stageK = [&](int tt, int buf) {           // 64 rows x 656 B = 2624 chunks
    const char* gK = gK0 + (size_t)tt * (64 * DPK * 2);
    char* lK = (char*)&Ksh[buf][0][0];
    #pragma unroll
    for (int i = 0; i < 6; ++i) {
      int c = i * 512 + tid;
      if (c < 2624) gl_lds16(gK + c * 16, lK + c * 16);
    }
  };
  auto stageV = [&](int tt) {                    // 304 rows x 9 slots (128 B data +
    const char* gV = gV0 + (size_t)tt * 128;     //  16 B benign overread) = 2736 chunks
    char* lV = (char*)&VTsh[0][0];
    #pragma unroll
    for (int i = 0; i < 6; ++i) {
      int c = i * 512 + tid;
      if (c < 2736) {
        int row = (int)((unsigned)c / 9u), slot = c - row * 9;
        gl_lds16(gV + (size_t)row * (NTP * 2) + slot * 16, lV + c * 16);
      }
    }
  };

  stageK(0, 0);                             // K[0] -> buf0
  asm volatile("s_waitcnt vmcnt(0)" ::: "memory");
  __builtin_amdgcn_s_barrier();
  __builtin_amdgcn_sched_barrier(0);

  #pragma unroll 1
  for (int t = 0; t < 32; ++t) {
    int kcur = t & 1;                       // K[t] buffer

    // ---- Phase 1: interleaved MFMA cluster — PV[t-1] / QK^T[t] half-blocks
    f32x16 S;
    #pragma unroll
    for (int e = 0; e < 16; ++e) S[e] = 0.f;
    __builtin_amdgcn_s_setprio(1);
    if (t > 0) {                            // PV half: ks 0,1 (kv 0..31 of tile t-1)
      #pragma unroll
      for (int ks = 0; ks < 2; ++ks) {
        f16x8 pf = *(const f16x8*)&Psh[qg][l31][ks * 16 + hi * 8];
        #pragma unroll
        for (int dt = 0; dt < 5; ++dt) {
          f16x8 vf = *(const f16x8*)&VTsh[dbase + dt * 32 + l31][ks * 16 + hi * 8];
          O[dt] = __builtin_amdgcn_mfma_f32_32x32x16_f16(vf, pf, O[dt], 0, 0, 0);
        }
      }
    }
    #pragma unroll
    for (int ks = 0; ks < 10; ++ks) {       // QK first half
      f16x8 a = *(const f16x8*)&Ksh[kcur][mem * 32 + l31][ks * 16 + hi * 8];
      S = __builtin_amdgcn_mfma_f32_32x32x16_f16(a, qf[ks], S, 0, 0, 0);
    }
    if (t > 0) {                            // PV half: ks 2,3 (kv 32..63)
      #pragma unroll
      for (int ks = 2; ks < 4; ++ks) {
        f16x8 pf = *(const f16x8*)&Psh[qg][l31][ks * 16 + hi * 8];
        #pragma unroll
        for (int dt = 0; dt < 5; ++dt) {
          f16x8 vf = *(const f16x8*)&VTsh[dbase + dt * 32 + l31][ks * 16 + hi * 8];
          O[dt] = __builtin_amdgcn_mfma_f32_32x32x16_f16(vf, pf, O[dt], 0, 0, 0);
        }
      }
    }
    #pragma unroll
    for (int ks = 10; ks < 20; ++ks) {      // QK second half
      f16x8 a = *(const f16x8*)&Ksh[kcur][mem * 32 + l31][ks * 16 + hi * 8];
      S = __builtin_amdgcn_mfma_f32_32x32x16_f16(a, qf[ks], S, 0, 0, 0);
    }
    __builtin_amdgcn_s_setprio(0);

    // ---- stage K[t+1] (dbuf; WAR-safe: buf readers finished before B2[t-1])
    if (t < 31) stageK(t + 1, kcur ^ 1);

    // ---- partial max over own 32 kv for q = l31 (16 in-lane + 1 shfl)
    float p = fmaxf(fmaxf(fmaxf(S[0], S[1]), S[2]),
                    fmaxf(fmaxf(S[3], S[4]), S[5]));
    p = fmaxf(p, fmaxf(fmaxf(S[6], S[7]), fmaxf(S[8], S[9])));
    p = fmaxf(p, fmaxf(fmaxf(S[10], S[11]), fmaxf(S[12], S[13])));
    p = fmaxf(p, fmaxf(S[14], S[15]));
    p = fmaxf(p, __shfl_xor(p, 32, 64));
    if (lane < 32) MxS[qg][mem][l31] = p;

    // ---- B1: Mx visible; all phase-1 reads of VTsh/Psh complete
    asm volatile("s_waitcnt lgkmcnt(0)" ::: "memory");
    __builtin_amdgcn_s_barrier();
    __builtin_amdgcn_sched_barrier(0);

    // ---- stage V[t] into the single buffer (race-free after B1)
    stageV(t);

    // ---- combine maxes, defer-max rescale, exp, P-write (no lsum adds:
    //      sum(P) accumulates in member1's O row 300 via the ones-row)
    float pp = MxS[qg][mem ^ 1][l31];
    float tm = fmaxf(p, pp);

    if (__any(tm > m + 8.0f)) {            // defer-max (identical in both members)
      float mn = fmaxf(m, tm), al = __expf(m - mn);
      #pragma unroll
      for (int dt = 0; dt < 5; ++dt)
        #pragma unroll
        for (int e = 0; e < 16; ++e) O[dt][e] *= al;
      m = mn;
    }

    #pragma unroll
    for (int r = 0; r < 4; ++r) {          // runs of 4 consecutive kv
      f16x4 h;
      #pragma unroll
      for (int j = 0; j < 4; ++j) {
        float e = __expf(S[4 * r + j] - m);   // bounded by e^8
        h[j] = (f16)e;
      }
      *(f16x4*)&Psh[qg][l31][mem * 32 + r * 8 + hi * 4] = h;
    }

    // ---- B2: P[t] visible; K[t+1] (issued ~2000 cyc ago) + V[t] drained
    asm volatile("s_waitcnt lgkmcnt(0) vmcnt(0)" ::: "memory");
    __builtin_amdgcn_s_barrier();
    __builtin_amdgcn_sched_barrier(0);
  }

  // ---- Epilogue PV[31] (trailing tile of the pipeline)
  {
    __builtin_amdgcn_s_setprio(1);
    #pragma unroll
    for (int ks = 0; ks < 4; ++ks) {
      f16x8 pf = *(const f16x8*)&Psh[qg][l31][ks * 16 + hi * 8];
      #pragma unroll
      for (int dt = 0; dt < 5; ++dt) {
        f16x8 vf = *(const f16x8*)&VTsh[dbase + dt * 32 + l31][ks * 16 + hi * 8];
        O[dt] = __builtin_amdgcn_mfma_f32_32x32x16_f16(vf, pf, O[dt], 0, 0, 0);
      }
    }
    __builtin_amdgcn_s_setprio(0);
  }

  // ---- lsum: member1's O[4][12] holds sum(P) at d=300 (hi=1 lanes only).
  //      Broadcast across hi, publish via MxS, both members read it.
  if (mem == 1) {
    float lt = O[4][12];
    float ls = __shfl_xor(lt, 32, 64);
    float l_tot = hi ? lt : ls;             // hi=0 lanes take partner's value
    if (lane < 32) MxS[qg][1][l31] = l_tot;
  }
  asm volatile("s_waitcnt lgkmcnt(0)" ::: "memory");
  __builtin_amdgcn_s_barrier();
  __builtin_amdgcn_sched_barrier(0);
  float rinv = 1.0f / MxS[qg][1][l31];

  // ---- store: d = dbase + dt*32 + r*8 + hi*4 + j (row 300 excluded by d0<300)
  {
    int q = qbase + l31;
    const f16* mrow = Qsrc + bq + (size_t)q * DPK;
    size_t orow = (size_t)b * (4096 * 300) + (size_t)(dir * 2048 + q) * 300;
    #pragma unroll
    for (int dt = 0; dt < 5; ++dt) {
      #pragma unroll
      for (int r = 0; r < 4; ++r) {
        int d0 = dbase + dt * 32 + r * 8 + hi * 4;
        if (d0 >= dlo && d0 < 300) {
          f16x4 mu = *(const f16x4*)(mrow + d0);
          f32x4 o;
          o[0] = O[dt][4 * r + 0] * rinv * (float)mu[0];
          o[1] = O[dt][4 * r + 1] * rinv * (float)mu[1];
          o[2] = O[dt][4 * r + 2] * rinv * (float)mu[2];
          o[3] = O[dt][4 * r + 3] * rinv * (float)mu[3];
          *(f32x4*)&out[orow + d0] = o;
        }
      }
    }
  }
}

extern "C" void kernel_launch(void* const* d_in, const int* in_sizes, int n_in,
                              void* d_out, int out_size, void* d_ws, size_t ws_size,
                              hipStream_t stream) {
  const float* X = (const float*)d_in[0];
  const float* Y = (const float*)d_in[1];
  float* out = (float*)d_out;

  size_t need = (size_t)(2 * XF_ELEMS + 2 * XT_ELEMS) * sizeof(f16);  // ~83 MB
  if (ws_size < need) return;

  // Layout: XT, YT first, Xf, Yf last — stageV's 16 B/row overread on the
  // transposed arrays lands in the following array, never past d_ws.
  f16* XT = (f16*)d_ws;
  f16* YT = XT + XT_ELEMS;
  f16* Xf = YT + XT_ELEMS;
  f16* Yf = Xf + XF_ELEMS;

  prep_kernel<<<dim3(65, 11, 32), 256, 0, stream>>>(X, Y, Xf, Yf, XT, YT);
  attn_kernel<<<dim3(512), 512, 0, stream>>>(Xf, Yf, XT, YT, out);
}